// Round 12
// baseline (358.391 us; speedup 1.0000x reference)
//
#include <hip/hip_runtime.h>

// GRU B=32,T=50,N=1024,C=128,H=64 via fp16 MFMA 16x16x32, fp32 accum.
// R12 = R10 (champion: 2048 blocks x 4 waves, block owns 16 seqs, wave jt owns
// 16 hidden cols, Wih quarter in regs, Whh in LDS, x staged to LDS f16 dbuf,
// lgkm-only barrier, setprio around MFMA, 4 blocks/CU) + instruction diet:
//   - accumulators init to per-lane BIAS (MFMA C-in pre-biased): -16 VALU/step
//   - 2-op blend hn = nn + z*(h-nn): -4 VALU/step
//   - zero register delta vs R10.

typedef _Float16 half8 __attribute__((ext_vector_type(8)));
typedef float f32x4 __attribute__((ext_vector_type(4)));

constexpr int T_ = 50, N_ = 1024, C_ = 128, H_ = 64;
constexpr uint32_t WHH_OFF = 0;       // 192 rows x 128B = 24576
constexpr uint32_t XB_OFF  = 24576;   // 2 x 4096 (16 seq x 128 f16) = 8192
constexpr uint32_t HB_OFF  = 32768;   // 2 x 2048 (16 seq x 64 f16)  = 4096
constexpr int LDS_BYTES = 36864;      // x4 blocks/CU = 147456 <= 163840

__global__ void prep_weights(const float* __restrict__ Wih, const float* __restrict__ Whh,
                             _Float16* __restrict__ w16) {
  int i = blockIdx.x * 256 + threadIdx.x;
  if (i < 192 * 128) w16[i] = (_Float16)Wih[i];
  if (i < 192 * 64)  w16[24576 + i] = (_Float16)Whh[i];
}

__device__ __forceinline__ half8 cvt8(float4 lo, float4 hi) {
  half8 v;
  v[0] = (_Float16)lo.x; v[1] = (_Float16)lo.y;
  v[2] = (_Float16)lo.z; v[3] = (_Float16)lo.w;
  v[4] = (_Float16)hi.x; v[5] = (_Float16)hi.y;
  v[6] = (_Float16)hi.z; v[7] = (_Float16)hi.w;
  return v;
}

__global__ __launch_bounds__(256, 4) void gru_diet(
    const float* __restrict__ x, const _Float16* __restrict__ w16,
    const float* __restrict__ bih, const float* __restrict__ bhh,
    float* __restrict__ out)
{
  __shared__ __align__(16) char lds[LDS_BYTES];
  const int tid = threadIdx.x;
  const int wv = tid >> 6, lane = tid & 63;
  const int c = lane & 15, g = lane >> 4;
  const int jt = wv;                               // this wave's col tile
  const int seq0 = blockIdx.x * 16;
  const int b = seq0 >> 10, n0 = seq0 & (N_ - 1);

  // ---- stage Whh into LDS (128B rows, granule ^= row&7); zero h bufs ----
  {
    const _Float16* whh = w16 + 24576;
#pragma unroll
    for (int rep = 0; rep < 6; ++rep) {            // 1536 16B chunks
      int i = tid + rep * 256;
      int row = i >> 3, gr = i & 7;
      uint32_t byte = (uint32_t)row * 128 + (uint32_t)((gr ^ (row & 7)) << 4);
      *(half8*)(lds + WHH_OFF + byte) = *(const half8*)(whh + i * 8);
    }
    half8 zz = {};
    *(half8*)(lds + HB_OFF + tid * 16) = zz;       // 4096 B both h bufs
  }

  // ---- Wih quarter in registers: wr[gate][ks], row = gate*64 + jt*16 + c ----
  half8 wr[3][4];
#pragma unroll
  for (int gate = 0; gate < 3; ++gate)
#pragma unroll
    for (int ks = 0; ks < 4; ++ks)
      wr[gate][ks] = *(const half8*)(w16 + (gate * 64 + jt * 16 + c) * 128 + ks * 32 + g * 8);

  // ---- per-lane biases for hidden col j = jt*16 + c (folded into acc init) ----
  const int j = jt * 16 + c;
  const float br   = bih[j] + bhh[j];
  const float bz   = bih[64 + j] + bhh[64 + j];
  const float bin_ = bih[128 + j];
  const float bhn_ = bhh[128 + j];

  float hr[4] = {0.f, 0.f, 0.f, 0.f};             // h carry for seq = g*4+v

  // ---- x staging mapping: thread -> (seq = tid>>4, ch0 = (tid&15)*8) ----
  const int sseq = tid >> 4;
  const uint32_t xw_off = (uint32_t)sseq * 256 +
                          (uint32_t)(((tid & 15) ^ (sseq & 7)) << 4);
  const float* xbase = x + ((size_t)b * T_ * N_ + n0 + sseq) * C_ + (tid & 15) * 8;
  const size_t stepstride = (size_t)N_ * C_;

#define WHHB(gate, ks2) \
  (*(const half8*)(lds + WHH_OFF + (uint32_t)(((gate) * 64 + jt * 16 + c) * 128) + \
                   (uint32_t)((((ks2) * 4 + g) ^ (c & 7)) << 4)))
#define MFMA16(a, bf, acc) __builtin_amdgcn_mfma_f32_16x16x32_f16((a), (bf), (acc), 0, 0, 0)

  // ---- prologue: stage x(0) into xbuf[0]; issue raw loads for x(1) ----
  {
    float4 r0 = *(const float4*)(xbase);
    float4 r1 = *(const float4*)(xbase + 4);
    *(half8*)(lds + XB_OFF + xw_off) = cvt8(r0, r1);
  }
  float4 ra = *(const float4*)(xbase + stepstride);
  float4 rb = *(const float4*)(xbase + stepstride + 4);
  __syncthreads();   // prologue only

  for (int t = 0; t < T_; ++t) {
    const uint32_t xr  = XB_OFF + (uint32_t)(t & 1) * 4096;
    const uint32_t hrd = HB_OFF + (uint32_t)((t + 1) & 1) * 2048;
    const uint32_t hwr = HB_OFF + (uint32_t)(t & 1) * 2048;

    // A-frags from LDS: x row = c (16 granules), h row = c (8 granules)
    half8 xa[4];
#pragma unroll
    for (int ks = 0; ks < 4; ++ks)
      xa[ks] = *(const half8*)(lds + xr + (uint32_t)c * 256 +
                               (uint32_t)(((ks * 4 + g) ^ (c & 7)) << 4));
    half8 ha[2];
#pragma unroll
    for (int ks2 = 0; ks2 < 2; ++ks2)
      ha[ks2] = *(const half8*)(lds + hrd + (uint32_t)c * 128 +
                                (uint32_t)(((ks2 * 4 + g) ^ (c & 7)) << 4));

    // accumulators pre-loaded with biases (saves 16 adds in the gate phase)
    f32x4 aR = {br, br, br, br}, aZ = {bz, bz, bz, bz};
    f32x4 aN = {bin_, bin_, bin_, bin_}, aH = {bhn_, bhn_, bhn_, bhn_};

    __builtin_amdgcn_s_setprio(1);
    // gi part (K=128, Wih from registers)
#pragma unroll
    for (int ks = 0; ks < 4; ++ks) {
      aR = MFMA16(xa[ks], wr[0][ks], aR);
      aZ = MFMA16(xa[ks], wr[1][ks], aZ);
      aN = MFMA16(xa[ks], wr[2][ks], aN);
    }
    // gh part (K=64, Whh from LDS)
#pragma unroll
    for (int ks2 = 0; ks2 < 2; ++ks2) {
      aR = MFMA16(ha[ks2], WHHB(0, ks2), aR);
      aZ = MFMA16(ha[ks2], WHHB(1, ks2), aZ);
      aH = MFMA16(ha[ks2], WHHB(2, ks2), aH);
    }
    __builtin_amdgcn_s_setprio(0);

    // gates (independent trans chains across v); lane holds D(seq=g*4+v, col j)
    float rr[4], zz4[4], nn[4];
#pragma unroll
    for (int v = 0; v < 4; ++v)
      rr[v] = __builtin_amdgcn_rcpf(1.f + __expf(-aR[v]));
#pragma unroll
    for (int v = 0; v < 4; ++v)
      zz4[v] = __builtin_amdgcn_rcpf(1.f + __expf(-aZ[v]));
#pragma unroll
    for (int v = 0; v < 4; ++v) {
      const float np = fmaf(rr[v], aH[v], aN[v]);
      nn[v] = fmaf(-2.f, __builtin_amdgcn_rcpf(__expf(2.f * np) + 1.f), 1.f);
    }
#pragma unroll
    for (int v = 0; v < 4; ++v) {
      const float hn = fmaf(zz4[v], hr[v] - nn[v], nn[v]);   // nn + z*(h-nn)
      hr[v] = hn;
      const int seq = g * 4 + v;
      const uint32_t gr = (uint32_t)((jt * 2 + (c >> 3)) ^ (seq & 7));
      *(_Float16*)(lds + hwr + (uint32_t)seq * 128 + (gr << 4) +
                   (uint32_t)((c & 7) * 2)) = (_Float16)hn;
    }

    // stage x(t+1) into xbuf[(t+1)&1]; issue raw loads for x(t+2)
    if (t + 1 < T_) {
      *(half8*)(lds + XB_OFF + (uint32_t)((t + 1) & 1) * 4096 + xw_off) = cvt8(ra, rb);
      const int tn2 = (t + 2 < T_) ? t + 2 : T_ - 1;
      const float* xp = xbase + (size_t)tn2 * stepstride;
      ra = *(const float4*)(xp);
      rb = *(const float4*)(xp + 4);
    }

    // publish LDS writes (h + x-stage) WITHOUT draining vmcnt
    asm volatile("s_waitcnt lgkmcnt(0)" ::: "memory");
    __builtin_amdgcn_s_barrier();
  }

  // ---- store final h (fp32 carry) ----
#pragma unroll
  for (int v = 0; v < 4; ++v)
    out[(size_t)(seq0 + g * 4 + v) * H_ + j] = hr[v];
#undef WHHB
#undef MFMA16
}

extern "C" void kernel_launch(void* const* d_in, const int* in_sizes, int n_in,
                              void* d_out, int out_size, void* d_ws, size_t ws_size,
                              hipStream_t stream) {
  const float* chars = (const float*)d_in[0];
  const float* Wih   = (const float*)d_in[1];
  const float* Whh   = (const float*)d_in[2];
  const float* bih   = (const float*)d_in[3];
  const float* bhh   = (const float*)d_in[4];

  _Float16* w16 = (_Float16*)d_ws;   // 36864 f16 = 73728 B

  prep_weights<<<96, 256, 0, stream>>>(Wih, Whh, w16);
  gru_diet<<<2048, 256, 0, stream>>>(chars, w16, bih, bhh, (float*)d_out);
}

// Round 13
// 223.079 us; speedup vs baseline: 1.6066x; 1.6066x over previous
//
#include <hip/hip_runtime.h>

// GRU B=32,T=50,N=1024,C=128,H=64 via fp16 MFMA 16x16x32, fp32 accum.
// R13 = R10 (champion: 2048 blocks x 4 waves, block owns 16 seqs, wave jt owns
// 16 hidden cols, Wih quarter in regs, Whh in LDS, x staged to LDS f16 dbuf,
// lgkm-only barrier, setprio around MFMA, 4 blocks/CU) + register-neutral diet:
//   - weights/biases pre-scaled by log2(e) (r,z rows) and 2*log2(e) (n rows)
//     in prep_weights -> __expf (v_mul+v_exp) becomes bare exp2f (v_exp):
//     -12 v_mul/wave-step off the serial trans chains
//   - 2-op blend hn = fmaf(z, h-nn, nn)
//   - loop structure byte-identical to R10 (R11/R12 lesson: any extra live
//     value at the (256,4) 128-VGPR cap spills).

typedef _Float16 half8 __attribute__((ext_vector_type(8)));
typedef float f32x4 __attribute__((ext_vector_type(4)));

constexpr int T_ = 50, N_ = 1024, C_ = 128, H_ = 64;
constexpr uint32_t WHH_OFF = 0;       // 192 rows x 128B = 24576
constexpr uint32_t XB_OFF  = 24576;   // 2 x 4096 (16 seq x 128 f16) = 8192
constexpr uint32_t HB_OFF  = 32768;   // 2 x 2048 (16 seq x 64 f16)  = 4096
constexpr int LDS_BYTES = 36864;      // x4 blocks/CU = 147456 <= 163840

#define L2E  1.4426950408889634f
#define T2E  2.8853900817779268f

__global__ void prep_weights(const float* __restrict__ Wih, const float* __restrict__ Whh,
                             _Float16* __restrict__ w16) {
  int i = blockIdx.x * 256 + threadIdx.x;
  if (i < 192 * 128) {
    const int row = i >> 7;
    const float s = (row < 128) ? L2E : T2E;
    w16[i] = (_Float16)(Wih[i] * s);
  }
  if (i < 192 * 64) {
    const int row = i >> 6;
    const float s = (row < 128) ? L2E : T2E;
    w16[24576 + i] = (_Float16)(Whh[i] * s);
  }
}

__device__ __forceinline__ half8 cvt8(float4 lo, float4 hi) {
  half8 v;
  v[0] = (_Float16)lo.x; v[1] = (_Float16)lo.y;
  v[2] = (_Float16)lo.z; v[3] = (_Float16)lo.w;
  v[4] = (_Float16)hi.x; v[5] = (_Float16)hi.y;
  v[6] = (_Float16)hi.z; v[7] = (_Float16)hi.w;
  return v;
}

__global__ __launch_bounds__(256, 4) void gru_e2(
    const float* __restrict__ x, const _Float16* __restrict__ w16,
    const float* __restrict__ bih, const float* __restrict__ bhh,
    float* __restrict__ out)
{
  __shared__ __align__(16) char lds[LDS_BYTES];
  const int tid = threadIdx.x;
  const int wv = tid >> 6, lane = tid & 63;
  const int c = lane & 15, g = lane >> 4;
  const int jt = wv;                               // this wave's col tile
  const int seq0 = blockIdx.x * 16;
  const int b = seq0 >> 10, n0 = seq0 & (N_ - 1);

  // ---- stage Whh into LDS (128B rows, granule ^= row&7); zero h bufs ----
  {
    const _Float16* whh = w16 + 24576;
#pragma unroll
    for (int rep = 0; rep < 6; ++rep) {            // 1536 16B chunks
      int i = tid + rep * 256;
      int row = i >> 3, gr = i & 7;
      uint32_t byte = (uint32_t)row * 128 + (uint32_t)((gr ^ (row & 7)) << 4);
      *(half8*)(lds + WHH_OFF + byte) = *(const half8*)(whh + i * 8);
    }
    half8 zz = {};
    *(half8*)(lds + HB_OFF + tid * 16) = zz;       // 4096 B both h bufs
  }

  // ---- Wih quarter in registers: wr[gate][ks], row = gate*64 + jt*16 + c ----
  half8 wr[3][4];
#pragma unroll
  for (int gate = 0; gate < 3; ++gate)
#pragma unroll
    for (int ks = 0; ks < 4; ++ks)
      wr[gate][ks] = *(const half8*)(w16 + (gate * 64 + jt * 16 + c) * 128 + ks * 32 + g * 8);

  // ---- per-lane biases for hidden col j = jt*16 + c (pre-scaled to exp2 domain) ----
  const int j = jt * 16 + c;
  const float br   = (bih[j] + bhh[j]) * L2E;
  const float bz   = (bih[64 + j] + bhh[64 + j]) * L2E;
  const float bin_ = bih[128 + j] * T2E;
  const float bhn_ = bhh[128 + j] * T2E;

  float hr[4] = {0.f, 0.f, 0.f, 0.f};             // h carry for seq = g*4+v

  // ---- x staging mapping: thread -> (seq = tid>>4, ch0 = (tid&15)*8) ----
  const int sseq = tid >> 4;
  const uint32_t xw_off = (uint32_t)sseq * 256 +
                          (uint32_t)(((tid & 15) ^ (sseq & 7)) << 4);
  const float* xbase = x + ((size_t)b * T_ * N_ + n0 + sseq) * C_ + (tid & 15) * 8;
  const size_t stepstride = (size_t)N_ * C_;

#define WHHB(gate, ks2) \
  (*(const half8*)(lds + WHH_OFF + (uint32_t)(((gate) * 64 + jt * 16 + c) * 128) + \
                   (uint32_t)((((ks2) * 4 + g) ^ (c & 7)) << 4)))
#define MFMA16(a, bf, acc) __builtin_amdgcn_mfma_f32_16x16x32_f16((a), (bf), (acc), 0, 0, 0)

  // ---- prologue: stage x(0) into xbuf[0]; issue raw loads for x(1) ----
  {
    float4 r0 = *(const float4*)(xbase);
    float4 r1 = *(const float4*)(xbase + 4);
    *(half8*)(lds + XB_OFF + xw_off) = cvt8(r0, r1);
  }
  float4 ra = *(const float4*)(xbase + stepstride);
  float4 rb = *(const float4*)(xbase + stepstride + 4);
  __syncthreads();   // prologue only

  for (int t = 0; t < T_; ++t) {
    const uint32_t xr  = XB_OFF + (uint32_t)(t & 1) * 4096;
    const uint32_t hrd = HB_OFF + (uint32_t)((t + 1) & 1) * 2048;
    const uint32_t hwr = HB_OFF + (uint32_t)(t & 1) * 2048;

    // A-frags from LDS: x row = c (16 granules), h row = c (8 granules)
    half8 xa[4];
#pragma unroll
    for (int ks = 0; ks < 4; ++ks)
      xa[ks] = *(const half8*)(lds + xr + (uint32_t)c * 256 +
                               (uint32_t)(((ks * 4 + g) ^ (c & 7)) << 4));
    half8 ha[2];
#pragma unroll
    for (int ks2 = 0; ks2 < 2; ++ks2)
      ha[ks2] = *(const half8*)(lds + hrd + (uint32_t)c * 128 +
                                (uint32_t)(((ks2 * 4 + g) ^ (c & 7)) << 4));

    f32x4 aR = {0.f, 0.f, 0.f, 0.f}, aZ = {0.f, 0.f, 0.f, 0.f};
    f32x4 aN = {0.f, 0.f, 0.f, 0.f}, aH = {0.f, 0.f, 0.f, 0.f};

    __builtin_amdgcn_s_setprio(1);
    // gi part (K=128, Wih from registers)
#pragma unroll
    for (int ks = 0; ks < 4; ++ks) {
      aR = MFMA16(xa[ks], wr[0][ks], aR);
      aZ = MFMA16(xa[ks], wr[1][ks], aZ);
      aN = MFMA16(xa[ks], wr[2][ks], aN);
    }
    // gh part (K=64, Whh from LDS)
#pragma unroll
    for (int ks2 = 0; ks2 < 2; ++ks2) {
      aR = MFMA16(ha[ks2], WHHB(0, ks2), aR);
      aZ = MFMA16(ha[ks2], WHHB(1, ks2), aZ);
      aH = MFMA16(ha[ks2], WHHB(2, ks2), aH);
    }
    __builtin_amdgcn_s_setprio(0);

    // gates (exp2 domain; weights pre-scaled): lane holds D(seq=g*4+v, col j)
#pragma unroll
    for (int v = 0; v < 4; ++v) {
      const float r = __builtin_amdgcn_rcpf(1.f + __builtin_exp2f(-(aR[v] + br)));
      const float z = __builtin_amdgcn_rcpf(1.f + __builtin_exp2f(-(aZ[v] + bz)));
      const float np = aN[v] + bin_ + r * (aH[v] + bhn_);   // = 2*log2e * npre
      const float nn = fmaf(-2.f, __builtin_amdgcn_rcpf(__builtin_exp2f(np) + 1.f), 1.f);
      const float hn = fmaf(z, hr[v] - nn, nn);             // nn + z*(h-nn)
      hr[v] = hn;
      const int seq = g * 4 + v;
      const uint32_t gr = (uint32_t)((jt * 2 + (c >> 3)) ^ (seq & 7));
      *(_Float16*)(lds + hwr + (uint32_t)seq * 128 + (gr << 4) +
                   (uint32_t)((c & 7) * 2)) = (_Float16)hn;
    }

    // stage x(t+1) into xbuf[(t+1)&1]; issue raw loads for x(t+2)
    if (t + 1 < T_) {
      *(half8*)(lds + XB_OFF + (uint32_t)((t + 1) & 1) * 4096 + xw_off) = cvt8(ra, rb);
      const int tn2 = (t + 2 < T_) ? t + 2 : T_ - 1;
      const float* xp = xbase + (size_t)tn2 * stepstride;
      ra = *(const float4*)(xp);
      rb = *(const float4*)(xp + 4);
    }

    // publish LDS writes (h + x-stage) WITHOUT draining vmcnt
    asm volatile("s_waitcnt lgkmcnt(0)" ::: "memory");
    __builtin_amdgcn_s_barrier();
  }

  // ---- store final h (fp32 carry) ----
#pragma unroll
  for (int v = 0; v < 4; ++v)
    out[(size_t)(seq0 + g * 4 + v) * H_ + j] = hr[v];
#undef WHHB
#undef MFMA16
}

extern "C" void kernel_launch(void* const* d_in, const int* in_sizes, int n_in,
                              void* d_out, int out_size, void* d_ws, size_t ws_size,
                              hipStream_t stream) {
  const float* chars = (const float*)d_in[0];
  const float* Wih   = (const float*)d_in[1];
  const float* Whh   = (const float*)d_in[2];
  const float* bih   = (const float*)d_in[3];
  const float* bhh   = (const float*)d_in[4];

  _Float16* w16 = (_Float16*)d_ws;   // 36864 f16 = 73728 B

  prep_weights<<<96, 256, 0, stream>>>(Wih, Whh, w16);
  gru_e2<<<2048, 256, 0, stream>>>(chars, w16, bih, bhh, (float*)d_out);
}

// Round 14
// 204.865 us; speedup vs baseline: 1.7494x; 1.0889x over previous
//
#include <hip/hip_runtime.h>

// GRU B=32,T=50,N=1024,C=128,H=64 via fp16 MFMA 16x16x32, fp32 accum.
// R14 = R10 shell + TWO INDEPENDENT CHAINS PER BLOCK (groups A/B of 16 seqs):
// within one barrier region the block computes A's full step AND B's full step
// -> B's 18 MFMAs fill A's gate/trans serial-spine stalls (and vice versa),
// and barriers per unit work halve. 1024 blocks x 4 waves; wave jt owns cols
// jt*16..+15 for BOTH groups. Wih quarter in regs, Whh in LDS, per-group x/h
// LDS dbufs, lgkm-only barrier, setprio around MFMA. 48KB LDS -> 3 blocks/CU.

typedef _Float16 half8 __attribute__((ext_vector_type(8)));
typedef float f32x4 __attribute__((ext_vector_type(4)));

constexpr int T_ = 50, N_ = 1024, C_ = 128, H_ = 64;
constexpr uint32_t WHH_OFF = 0;       // 192 rows x 128B = 24576
// x bufs: XB(grp,p) = 24576 + grp*8192 + p*4096   (16 seq x 128 f16 each)
// h bufs: HB(grp,p) = 40960 + grp*4096 + p*2048   (16 seq x  64 f16 each)
constexpr int LDS_BYTES = 49152;      // x3 blocks/CU = 147456 <= 163840

__global__ void prep_weights(const float* __restrict__ Wih, const float* __restrict__ Whh,
                             _Float16* __restrict__ w16) {
  int i = blockIdx.x * 256 + threadIdx.x;
  if (i < 192 * 128) w16[i] = (_Float16)Wih[i];
  if (i < 192 * 64)  w16[24576 + i] = (_Float16)Whh[i];
}

__device__ __forceinline__ float sigm(float x) {
  return __builtin_amdgcn_rcpf(1.f + __expf(-x));
}

__device__ __forceinline__ half8 cvt8(float4 lo, float4 hi) {
  half8 v;
  v[0] = (_Float16)lo.x; v[1] = (_Float16)lo.y;
  v[2] = (_Float16)lo.z; v[3] = (_Float16)lo.w;
  v[4] = (_Float16)hi.x; v[5] = (_Float16)hi.y;
  v[6] = (_Float16)hi.z; v[7] = (_Float16)hi.w;
  return v;
}

__global__ __launch_bounds__(256, 3) void gru_dual(
    const float* __restrict__ x, const _Float16* __restrict__ w16,
    const float* __restrict__ bih, const float* __restrict__ bhh,
    float* __restrict__ out)
{
  __shared__ __align__(16) char lds[LDS_BYTES];
  const int tid = threadIdx.x;
  const int wv = tid >> 6, lane = tid & 63;
  const int c = lane & 15, g = lane >> 4;
  const int jt = wv;                               // this wave's col tile
  const int seq0 = blockIdx.x * 32;                // 32 seqs: A=0..15, B=16..31
  const int b = seq0 >> 10, n0 = seq0 & (N_ - 1);

  // ---- stage Whh into LDS (128B rows, granule ^= row&7); zero all h bufs ----
  {
    const _Float16* whh = w16 + 24576;
#pragma unroll
    for (int rep = 0; rep < 6; ++rep) {            // 1536 16B chunks
      int i = tid + rep * 256;
      int row = i >> 3, gr = i & 7;
      uint32_t byte = (uint32_t)row * 128 + (uint32_t)((gr ^ (row & 7)) << 4);
      *(half8*)(lds + WHH_OFF + byte) = *(const half8*)(whh + i * 8);
    }
    half8 zz = {};
    *(half8*)(lds + 40960 + tid * 32)      = zz;   // 8192 B = all 4 h bufs
    *(half8*)(lds + 40960 + tid * 32 + 16) = zz;
  }

  // ---- Wih quarter in registers: wr[gate][ks], row = gate*64 + jt*16 + c ----
  half8 wr[3][4];
#pragma unroll
  for (int gate = 0; gate < 3; ++gate)
#pragma unroll
    for (int ks = 0; ks < 4; ++ks)
      wr[gate][ks] = *(const half8*)(w16 + (gate * 64 + jt * 16 + c) * 128 + ks * 32 + g * 8);

  // ---- per-lane biases for hidden col j = jt*16 + c ----
  const int j = jt * 16 + c;
  const float br   = bih[j] + bhh[j];
  const float bz   = bih[64 + j] + bhh[64 + j];
  const float bin_ = bih[128 + j];
  const float bhn_ = bhh[128 + j];

  float hr[8];                                     // h carry: grp*4 + v
#pragma unroll
  for (int i = 0; i < 8; ++i) hr[i] = 0.f;

  // ---- x staging mapping: thread -> (seq = tid>>4, ch0 = (tid&15)*8) ----
  const int sseq = tid >> 4;
  const uint32_t xw_off = (uint32_t)sseq * 256 +
                          (uint32_t)(((tid & 15) ^ (sseq & 7)) << 4);
  const float* xbaseA = x + ((size_t)b * T_ * N_ + n0 + sseq) * C_ + (tid & 15) * 8;
  const float* xbaseB = xbaseA + 16 * C_;          // seqs n0+16..n0+31
  const size_t stepstride = (size_t)N_ * C_;

#define WHHB(gate, ks2) \
  (*(const half8*)(lds + WHH_OFF + (uint32_t)(((gate) * 64 + jt * 16 + c) * 128) + \
                   (uint32_t)((((ks2) * 4 + g) ^ (c & 7)) << 4)))
#define MFMA16(a, bf, acc) __builtin_amdgcn_mfma_f32_16x16x32_f16((a), (bf), (acc), 0, 0, 0)

  // ---- prologue: stage x(0) A+B; issue raw loads for x(1) A+B ----
  {
    float4 r0 = *(const float4*)(xbaseA);
    float4 r1 = *(const float4*)(xbaseA + 4);
    *(half8*)(lds + 24576 + xw_off) = cvt8(r0, r1);
    float4 r2 = *(const float4*)(xbaseB);
    float4 r3 = *(const float4*)(xbaseB + 4);
    *(half8*)(lds + 24576 + 8192 + xw_off) = cvt8(r2, r3);
  }
  float4 rA0 = *(const float4*)(xbaseA + stepstride);
  float4 rA1 = *(const float4*)(xbaseA + stepstride + 4);
  float4 rB0 = *(const float4*)(xbaseB + stepstride);
  float4 rB1 = *(const float4*)(xbaseB + stepstride + 4);
  __syncthreads();   // prologue only

  // full step for one group (compute + gates + h-write), R10 semantics
#define COMPUTE(grp)                                                            \
  do {                                                                          \
    const uint32_t xr  = 24576u + (grp) * 8192u + (uint32_t)(t & 1) * 4096;     \
    const uint32_t hrd = 40960u + (grp) * 4096u + (uint32_t)((t + 1) & 1) * 2048; \
    const uint32_t hwr = 40960u + (grp) * 4096u + (uint32_t)(t & 1) * 2048;     \
    half8 xa[4];                                                                \
    _Pragma("unroll")                                                           \
    for (int ks = 0; ks < 4; ++ks)                                              \
      xa[ks] = *(const half8*)(lds + xr + (uint32_t)c * 256 +                   \
                               (uint32_t)(((ks * 4 + g) ^ (c & 7)) << 4));      \
    half8 ha[2];                                                                \
    _Pragma("unroll")                                                           \
    for (int ks2 = 0; ks2 < 2; ++ks2)                                           \
      ha[ks2] = *(const half8*)(lds + hrd + (uint32_t)c * 128 +                 \
                                (uint32_t)(((ks2 * 4 + g) ^ (c & 7)) << 4));    \
    f32x4 aR = {0.f, 0.f, 0.f, 0.f}, aZ = {0.f, 0.f, 0.f, 0.f};                 \
    f32x4 aN = {0.f, 0.f, 0.f, 0.f}, aH = {0.f, 0.f, 0.f, 0.f};                 \
    __builtin_amdgcn_s_setprio(1);                                              \
    _Pragma("unroll")                                                           \
    for (int ks = 0; ks < 4; ++ks) {                                            \
      aR = MFMA16(xa[ks], wr[0][ks], aR);                                       \
      aZ = MFMA16(xa[ks], wr[1][ks], aZ);                                       \
      aN = MFMA16(xa[ks], wr[2][ks], aN);                                       \
    }                                                                           \
    _Pragma("unroll")                                                           \
    for (int ks2 = 0; ks2 < 2; ++ks2) {                                         \
      aR = MFMA16(ha[ks2], WHHB(0, ks2), aR);                                   \
      aZ = MFMA16(ha[ks2], WHHB(1, ks2), aZ);                                   \
      aH = MFMA16(ha[ks2], WHHB(2, ks2), aH);                                   \
    }                                                                           \
    __builtin_amdgcn_s_setprio(0);                                              \
    _Pragma("unroll")                                                           \
    for (int v = 0; v < 4; ++v) {                                               \
      const float r = sigm(aR[v] + br);                                         \
      const float z = sigm(aZ[v] + bz);                                         \
      const float np = aN[v] + bin_ + r * (aH[v] + bhn_);                       \
      const float nn = 1.f - 2.f * __builtin_amdgcn_rcpf(__expf(2.f * np) + 1.f); \
      const float hn = (1.f - z) * nn + z * hr[(grp) * 4 + v];                  \
      hr[(grp) * 4 + v] = hn;                                                   \
      const int seq = g * 4 + v;                                                \
      const uint32_t gr = (uint32_t)((jt * 2 + (c >> 3)) ^ (seq & 7));          \
      *(_Float16*)(lds + hwr + (uint32_t)seq * 128 + (gr << 4) +                \
                   (uint32_t)((c & 7) * 2)) = (_Float16)hn;                     \
    }                                                                           \
  } while (0)

#define STAGE(grp, RA, RB, XB)                                                  \
  if (t + 1 < T_) {                                                             \
    *(half8*)(lds + 24576u + (grp) * 8192u + (uint32_t)((t + 1) & 1) * 4096 +   \
              xw_off) = cvt8(RA, RB);                                           \
    const int tn2 = (t + 2 < T_) ? t + 2 : T_ - 1;                              \
    const float* xp = (XB) + (size_t)tn2 * stepstride;                          \
    RA = *(const float4*)(xp);                                                  \
    RB = *(const float4*)(xp + 4);                                              \
  }

  for (int t = 0; t < T_; ++t) {
    COMPUTE(0);                      // A full step
    COMPUTE(1);                      // B full step — independent: fills A stalls
    STAGE(0, rA0, rA1, xbaseA);
    STAGE(1, rB0, rB1, xbaseB);
    // publish LDS writes (h + x-stage) WITHOUT draining vmcnt
    asm volatile("s_waitcnt lgkmcnt(0)" ::: "memory");
    __builtin_amdgcn_s_barrier();
  }

  // ---- store final h (fp32 carry) ----
#pragma unroll
  for (int grp = 0; grp < 2; ++grp)
#pragma unroll
    for (int v = 0; v < 4; ++v)
      out[(size_t)(seq0 + grp * 16 + g * 4 + v) * H_ + j] = hr[grp * 4 + v];
#undef COMPUTE
#undef STAGE
#undef WHHB
#undef MFMA16
}

extern "C" void kernel_launch(void* const* d_in, const int* in_sizes, int n_in,
                              void* d_out, int out_size, void* d_ws, size_t ws_size,
                              hipStream_t stream) {
  const float* chars = (const float*)d_in[0];
  const float* Wih   = (const float*)d_in[1];
  const float* Whh   = (const float*)d_in[2];
  const float* bih   = (const float*)d_in[3];
  const float* bhh   = (const float*)d_in[4];

  _Float16* w16 = (_Float16*)d_ws;   // 36864 f16 = 73728 B

  prep_weights<<<96, 256, 0, stream>>>(Wih, Whh, w16);
  gru_dual<<<1024, 256, 0, stream>>>(chars, w16, bih, bhh, (float*)d_out);
}

// Round 15
// 204.526 us; speedup vs baseline: 1.7523x; 1.0017x over previous
//
#include <hip/hip_runtime.h>

// GRU B=32,T=50,N=1024,C=128,H=64 via fp16 MFMA 16x16x32, fp32 accum.
// R15 = R10 (champion: 2048 blocks x 4 waves, block owns 16 seqs, wave jt owns
// 16 hidden cols, Wih quarter in regs, Whh in LDS, x staged to LDS f16 dbuf,
// lgkm-only barrier, setprio around MFMA, 4 blocks/CU) + NON-TEMPORAL x loads:
// x is read-once streaming (839 MB, zero reuse) -- the nt bit skips L2
// allocation, removing fill/evict overhead from the only hot path left.
// Zero register / schedule delta vs R10.

typedef _Float16 half8 __attribute__((ext_vector_type(8)));
typedef float f32x4 __attribute__((ext_vector_type(4)));
typedef float f32x4e __attribute__((ext_vector_type(4)));

constexpr int T_ = 50, N_ = 1024, C_ = 128, H_ = 64;
constexpr uint32_t WHH_OFF = 0;       // 192 rows x 128B = 24576
constexpr uint32_t XB_OFF  = 24576;   // 2 x 4096 (16 seq x 128 f16) = 8192
constexpr uint32_t HB_OFF  = 32768;   // 2 x 2048 (16 seq x 64 f16)  = 4096
constexpr int LDS_BYTES = 36864;      // x4 blocks/CU = 147456 <= 163840

__global__ void prep_weights(const float* __restrict__ Wih, const float* __restrict__ Whh,
                             _Float16* __restrict__ w16) {
  int i = blockIdx.x * 256 + threadIdx.x;
  if (i < 192 * 128) w16[i] = (_Float16)Wih[i];
  if (i < 192 * 64)  w16[24576 + i] = (_Float16)Whh[i];
}

__device__ __forceinline__ float sigm(float x) {
  return __builtin_amdgcn_rcpf(1.f + __expf(-x));
}

__device__ __forceinline__ float4 ntload4(const float* p) {
  f32x4e v = __builtin_nontemporal_load((const f32x4e*)p);
  return *(float4*)&v;
}

__device__ __forceinline__ half8 cvt8(float4 lo, float4 hi) {
  half8 v;
  v[0] = (_Float16)lo.x; v[1] = (_Float16)lo.y;
  v[2] = (_Float16)lo.z; v[3] = (_Float16)lo.w;
  v[4] = (_Float16)hi.x; v[5] = (_Float16)hi.y;
  v[6] = (_Float16)hi.z; v[7] = (_Float16)hi.w;
  return v;
}

__global__ __launch_bounds__(256, 4) void gru_nt(
    const float* __restrict__ x, const _Float16* __restrict__ w16,
    const float* __restrict__ bih, const float* __restrict__ bhh,
    float* __restrict__ out)
{
  __shared__ __align__(16) char lds[LDS_BYTES];
  const int tid = threadIdx.x;
  const int wv = tid >> 6, lane = tid & 63;
  const int c = lane & 15, g = lane >> 4;
  const int jt = wv;                               // this wave's col tile
  const int seq0 = blockIdx.x * 16;
  const int b = seq0 >> 10, n0 = seq0 & (N_ - 1);

  // ---- stage Whh into LDS (128B rows, granule ^= row&7); zero h bufs ----
  {
    const _Float16* whh = w16 + 24576;
#pragma unroll
    for (int rep = 0; rep < 6; ++rep) {            // 1536 16B chunks
      int i = tid + rep * 256;
      int row = i >> 3, gr = i & 7;
      uint32_t byte = (uint32_t)row * 128 + (uint32_t)((gr ^ (row & 7)) << 4);
      *(half8*)(lds + WHH_OFF + byte) = *(const half8*)(whh + i * 8);
    }
    half8 zz = {};
    *(half8*)(lds + HB_OFF + tid * 16) = zz;       // 4096 B both h bufs
  }

  // ---- Wih quarter in registers: wr[gate][ks], row = gate*64 + jt*16 + c ----
  half8 wr[3][4];
#pragma unroll
  for (int gate = 0; gate < 3; ++gate)
#pragma unroll
    for (int ks = 0; ks < 4; ++ks)
      wr[gate][ks] = *(const half8*)(w16 + (gate * 64 + jt * 16 + c) * 128 + ks * 32 + g * 8);

  // ---- per-lane biases for hidden col j = jt*16 + c ----
  const int j = jt * 16 + c;
  const float br   = bih[j] + bhh[j];
  const float bz   = bih[64 + j] + bhh[64 + j];
  const float bin_ = bih[128 + j];
  const float bhn_ = bhh[128 + j];

  float hr[4] = {0.f, 0.f, 0.f, 0.f};             // h carry for seq = g*4+v

  // ---- x staging mapping: thread -> (seq = tid>>4, ch0 = (tid&15)*8) ----
  const int sseq = tid >> 4;
  const uint32_t xw_off = (uint32_t)sseq * 256 +
                          (uint32_t)(((tid & 15) ^ (sseq & 7)) << 4);
  const float* xbase = x + ((size_t)b * T_ * N_ + n0 + sseq) * C_ + (tid & 15) * 8;
  const size_t stepstride = (size_t)N_ * C_;

#define WHHB(gate, ks2) \
  (*(const half8*)(lds + WHH_OFF + (uint32_t)(((gate) * 64 + jt * 16 + c) * 128) + \
                   (uint32_t)((((ks2) * 4 + g) ^ (c & 7)) << 4)))
#define MFMA16(a, bf, acc) __builtin_amdgcn_mfma_f32_16x16x32_f16((a), (bf), (acc), 0, 0, 0)

  // ---- prologue: stage x(0) into xbuf[0]; issue raw loads for x(1) ----
  {
    float4 r0 = ntload4(xbase);
    float4 r1 = ntload4(xbase + 4);
    *(half8*)(lds + XB_OFF + xw_off) = cvt8(r0, r1);
  }
  float4 ra = ntload4(xbase + stepstride);
  float4 rb = ntload4(xbase + stepstride + 4);
  __syncthreads();   // prologue only

  for (int t = 0; t < T_; ++t) {
    const uint32_t xr  = XB_OFF + (uint32_t)(t & 1) * 4096;
    const uint32_t hrd = HB_OFF + (uint32_t)((t + 1) & 1) * 2048;
    const uint32_t hwr = HB_OFF + (uint32_t)(t & 1) * 2048;

    // A-frags from LDS: x row = c (16 granules), h row = c (8 granules)
    half8 xa[4];
#pragma unroll
    for (int ks = 0; ks < 4; ++ks)
      xa[ks] = *(const half8*)(lds + xr + (uint32_t)c * 256 +
                               (uint32_t)(((ks * 4 + g) ^ (c & 7)) << 4));
    half8 ha[2];
#pragma unroll
    for (int ks2 = 0; ks2 < 2; ++ks2)
      ha[ks2] = *(const half8*)(lds + hrd + (uint32_t)c * 128 +
                                (uint32_t)(((ks2 * 4 + g) ^ (c & 7)) << 4));

    f32x4 aR = {0.f, 0.f, 0.f, 0.f}, aZ = {0.f, 0.f, 0.f, 0.f};
    f32x4 aN = {0.f, 0.f, 0.f, 0.f}, aH = {0.f, 0.f, 0.f, 0.f};

    __builtin_amdgcn_s_setprio(1);
    // gi part (K=128, Wih from registers)
#pragma unroll
    for (int ks = 0; ks < 4; ++ks) {
      aR = MFMA16(xa[ks], wr[0][ks], aR);
      aZ = MFMA16(xa[ks], wr[1][ks], aZ);
      aN = MFMA16(xa[ks], wr[2][ks], aN);
    }
    // gh part (K=64, Whh from LDS)
#pragma unroll
    for (int ks2 = 0; ks2 < 2; ++ks2) {
      aR = MFMA16(ha[ks2], WHHB(0, ks2), aR);
      aZ = MFMA16(ha[ks2], WHHB(1, ks2), aZ);
      aH = MFMA16(ha[ks2], WHHB(2, ks2), aH);
    }
    __builtin_amdgcn_s_setprio(0);

    // gates: lane holds D(seq = g*4+v, col j); write h(t) to hbuf[t&1]
#pragma unroll
    for (int v = 0; v < 4; ++v) {
      const float r = sigm(aR[v] + br);
      const float z = sigm(aZ[v] + bz);
      const float np = aN[v] + bin_ + r * (aH[v] + bhn_);
      const float nn = 1.f - 2.f * __builtin_amdgcn_rcpf(__expf(2.f * np) + 1.f);
      const float hn = (1.f - z) * nn + z * hr[v];
      hr[v] = hn;
      const int seq = g * 4 + v;
      const uint32_t gr = (uint32_t)((jt * 2 + (c >> 3)) ^ (seq & 7));
      *(_Float16*)(lds + hwr + (uint32_t)seq * 128 + (gr << 4) +
                   (uint32_t)((c & 7) * 2)) = (_Float16)hn;
    }

    // stage x(t+1) into xbuf[(t+1)&1]; issue raw loads for x(t+2)
    if (t + 1 < T_) {
      *(half8*)(lds + XB_OFF + (uint32_t)((t + 1) & 1) * 4096 + xw_off) = cvt8(ra, rb);
      const int tn2 = (t + 2 < T_) ? t + 2 : T_ - 1;
      const float* xp = xbase + (size_t)tn2 * stepstride;
      ra = ntload4(xp);
      rb = ntload4(xp + 4);
    }

    // publish LDS writes (h + x-stage) WITHOUT draining vmcnt
    asm volatile("s_waitcnt lgkmcnt(0)" ::: "memory");
    __builtin_amdgcn_s_barrier();
  }

  // ---- store final h (fp32 carry) ----
#pragma unroll
  for (int v = 0; v < 4; ++v)
    out[(size_t)(seq0 + g * 4 + v) * H_ + j] = hr[v];
#undef WHHB
#undef MFMA16
}

extern "C" void kernel_launch(void* const* d_in, const int* in_sizes, int n_in,
                              void* d_out, int out_size, void* d_ws, size_t ws_size,
                              hipStream_t stream) {
  const float* chars = (const float*)d_in[0];
  const float* Wih   = (const float*)d_in[1];
  const float* Whh   = (const float*)d_in[2];
  const float* bih   = (const float*)d_in[3];
  const float* bhh   = (const float*)d_in[4];

  _Float16* w16 = (_Float16*)d_ws;   // 36864 f16 = 73728 B

  prep_weights<<<96, 256, 0, stream>>>(Wih, Whh, w16);
  gru_nt<<<2048, 256, 0, stream>>>(chars, w16, bih, bhh, (float*)d_out);
}